// Round 1
// baseline (1719.823 us; speedup 1.0000x reference)
//
#include <hip/hip_runtime.h>
#include <math.h>

#define LSEQ 36864          // 192*192
#define NCH  256            // scan chunks
#define CLEN 144            // chunk length (256*144 = 36864)
#define HH   192
#define WW   192

// misc region layout (float offsets)
#define LAMRE_OFF 0         // 2*64
#define LAMIM_OFF 128       // 2*64
#define BB_OFF    256       // 2*128*64 = 16384
#define CARRY_OFF 32768     // 4*2*256*64*2 = 262144
#define CIN_OFF   524288    // 262144
#define MISC_N    (1u<<20)  // 4 MB of floats

__device__ __forceinline__ float gelu_f(float x) {
  float x3 = x * x * x;
  return 0.5f * x * (1.f + tanhf(0.79788456080286535588f * (x + 0.044715f * x3)));
}

// ---------------- setup: lam_bar and B_bar ----------------
__global__ void k_setup(const float* __restrict__ lam_re, const float* __restrict__ lam_im,
                        const float* __restrict__ B_re, const float* __restrict__ B_im,
                        const float* __restrict__ log_step, float* __restrict__ misc) {
  const int i = blockIdx.x, p = threadIdx.x;
  const float lr = lam_re[i * 64 + p], li = lam_im[i * 64 + p];
  const float dt = expf(log_step[i * 64 + p]);
  const float er = expf(lr * dt);
  const float lbr = er * cosf(li * dt), lbi = er * sinf(li * dt);
  misc[LAMRE_OFF + i * 64 + p] = lbr;
  misc[LAMIM_OFF + i * 64 + p] = lbi;
  const float nr = lbr - 1.f, ni = lbi;
  const float den = lr * lr + li * li;
  const float fr = (nr * lr + ni * li) / den, fi = (ni * lr - nr * li) / den;
  for (int c = 0; c < 64; ++c) {
    float br = B_re[i * 4096 + p * 64 + c], bi = B_im[i * 4096 + p * 64 + c];
    misc[BB_OFF + i * 8192 + p * 64 + c]        = fr * br - fi * bi;  // re rows 0..63
    misc[BB_OFF + i * 8192 + (64 + p) * 64 + c] = fr * bi + fi * br;  // im rows 64..127
  }
}

// ---------------- LN1 + Bu GEMM ----------------
// xin: (b, C, L) seq-major.  fx: (b, L, C).  bu_{re,im}: (b, L, P)
__global__ __launch_bounds__(256) void k_ln_bu(
    const float* __restrict__ xin, const float* __restrict__ g, const float* __restrict__ be,
    const float* __restrict__ BB, float* __restrict__ fx,
    float* __restrict__ bure, float* __restrict__ buim) {
  __shared__ float tBig[128][65];   // staging (rows=channel) then Bu output (rows=p|64+p)
  __shared__ float tB[64][65];      // normalized fx, [pos][c]
  const int tid = threadIdx.x, blk = blockIdx.x;
  const int bb = blk / (LSEQ / 64);
  const int l0 = (blk % (LSEQ / 64)) * 64;
  const float* xp = xin + (size_t)bb * 64 * LSEQ + l0;
#pragma unroll
  for (int k = 0; k < 16; ++k) {
    int idx = tid + k * 256; int r = idx >> 6, c = idx & 63;
    tBig[r][c] = xp[(size_t)r * LSEQ + c];
  }
  __syncthreads();
  const int pos = tid & 63, q = tid >> 6;
  float s = 0.f, s2 = 0.f;
#pragma unroll
  for (int c = 0; c < 64; ++c) { float v = tBig[c][pos]; s += v; s2 += v * v; }
  float mu = s * (1.f / 64.f);
  float rs = rsqrtf(fmaxf(s2 * (1.f / 64.f) - mu * mu, 0.f) + 1e-5f);
#pragma unroll
  for (int u = 0; u < 16; ++u) {
    int c = q * 16 + u;
    tB[pos][c] = (tBig[c][pos] - mu) * rs * g[c] + be[c];
  }
  __syncthreads();
  const size_t rowbase = ((size_t)bb * LSEQ + l0) * 64;
#pragma unroll
  for (int k = 0; k < 16; ++k) {
    int idx = tid + k * 256;
    fx[rowbase + idx] = tB[idx >> 6][idx & 63];
  }
  // Bu: this thread computes rows rbase..rbase+31 (0..63 = re, 64..127 = im)
  const int rbase = q * 32;
  float acc[32];
#pragma unroll
  for (int j = 0; j < 32; ++j) acc[j] = 0.f;
  for (int c0 = 0; c0 < 64; c0 += 8) {
    float vv[8];
#pragma unroll
    for (int u = 0; u < 8; ++u) vv[u] = tB[pos][c0 + u];
#pragma unroll
    for (int j = 0; j < 32; ++j) {
      const float* wr = BB + (rbase + j) * 64 + c0;
      float d = 0.f;
#pragma unroll
      for (int u = 0; u < 8; ++u) d += wr[u] * vv[u];
      acc[j] += d;
    }
  }
#pragma unroll
  for (int j = 0; j < 32; ++j) tBig[rbase + j][pos] = acc[j];
  __syncthreads();
#pragma unroll
  for (int k = 0; k < 16; ++k) {
    int idx = tid + k * 256; int lr_ = idx >> 6, p = idx & 63;
    bure[rowbase + (size_t)lr_ * 64 + p] = tBig[p][lr_];
    buim[rowbase + (size_t)lr_ * 64 + p] = tBig[64 + p][lr_];
  }
}

// ---------------- scan phase 1: per-chunk local carries ----------------
__global__ __launch_bounds__(256) void k_scan1(
    const float* __restrict__ bure, const float* __restrict__ buim,
    const float* __restrict__ lre, const float* __restrict__ lim,
    float* __restrict__ carry) {
  const int wid = blockIdx.x * 4 + (threadIdx.x >> 6);
  const int p = threadIdx.x & 63;
  const int chunk = wid & (NCH - 1);
  const int dir = (wid >> 8) & 1;
  const int bb = wid >> 9;
  const float lr = lre[p], li = lim[p];
  float xr = 0.f, xi = 0.f;
  if (dir == 0) {
    size_t base = ((size_t)bb * LSEQ + (size_t)chunk * CLEN) * 64 + p;
#pragma unroll 4
    for (int k = 0; k < CLEN; ++k) {
      float br = bure[base], bi = buim[base];
      float nr = fmaf(lr, xr, fmaf(-li, xi, br));
      float ni = fmaf(lr, xi, fmaf(li, xr, bi));
      xr = nr; xi = ni; base += 64;
    }
  } else {
    size_t base = ((size_t)bb * LSEQ + (size_t)(LSEQ - 1 - chunk * CLEN)) * 64 + p;
#pragma unroll 4
    for (int k = 0; k < CLEN; ++k) {
      float br = bure[base], bi = buim[base];
      float nr = fmaf(lr, xr, fmaf(-li, xi, br));
      float ni = fmaf(lr, xi, fmaf(li, xr, bi));
      xr = nr; xi = ni; base -= 64;
    }
  }
  size_t co = (((size_t)(bb * 2 + dir) * NCH + chunk) * 64 + p) * 2;
  carry[co] = xr; carry[co + 1] = xi;
}

// ---------------- scan phase 2: carry prefix (one wave per (b,dir)) ----------------
__global__ __launch_bounds__(512) void k_scan2(
    const float* __restrict__ lre, const float* __restrict__ lim,
    const float* __restrict__ carry, float* __restrict__ cin) {
  const int wv = threadIdx.x >> 6, p = threadIdx.x & 63;
  const int dir = wv & 1, bb = wv >> 1;
  const float lr = lre[p], li = lim[p];
  float dr = 1.f, di = 0.f, br = lr, bi = li;   // lam^CLEN by squaring
  int e = CLEN;
  while (e) {
    if (e & 1) { float t = dr * br - di * bi; di = dr * bi + di * br; dr = t; }
    float t2 = br * br - bi * bi; bi = 2.f * br * bi; br = t2;
    e >>= 1;
  }
  float xr = 0.f, xi = 0.f;
  size_t base0 = ((size_t)(bb * 2 + dir) * NCH) * 64 + p;
  for (int j = 0; j < NCH; ++j) {
    size_t o = (base0 + (size_t)j * 64) * 2;
    cin[o] = xr; cin[o + 1] = xi;
    float cr = carry[o], ci = carry[o + 1];
    float nr = fmaf(dr, xr, fmaf(-di, xi, cr));
    float ni = fmaf(dr, xi, fmaf(di, xr, ci));
    xr = nr; xi = ni;
  }
}

// ---------------- scan phase 3: recompute with correct init, write states ----------------
// NOTE: for dir==1, (xre,xim) alias (bure,buim): intentional in-place, no __restrict__.
__global__ __launch_bounds__(256) void k_scan3(
    const float* bure, const float* buim,
    const float* __restrict__ lre, const float* __restrict__ lim,
    const float* __restrict__ cin, const int dir,
    float* xre, float* xim) {
  const int wid = blockIdx.x * 4 + (threadIdx.x >> 6);
  const int p = threadIdx.x & 63;
  const int chunk = wid & (NCH - 1);
  const int bb = wid >> 8;
  const float lr = lre[p], li = lim[p];
  size_t co = (((size_t)(bb * 2 + dir) * NCH + chunk) * 64 + p) * 2;
  float xr = cin[co], xi = cin[co + 1];
  if (dir == 0) {
    size_t base = ((size_t)bb * LSEQ + (size_t)chunk * CLEN) * 64 + p;
#pragma unroll 4
    for (int k = 0; k < CLEN; ++k) {
      float br = bure[base], bi = buim[base];
      float nr = fmaf(lr, xr, fmaf(-li, xi, br));
      float ni = fmaf(lr, xi, fmaf(li, xr, bi));
      xr = nr; xi = ni;
      xre[base] = xr; xim[base] = xi;
      base += 64;
    }
  } else {
    size_t base = ((size_t)bb * LSEQ + (size_t)(LSEQ - 1 - chunk * CLEN)) * 64 + p;
#pragma unroll 4
    for (int k = 0; k < CLEN; ++k) {
      float br = bure[base], bi = buim[base];
      float nr = fmaf(lr, xr, fmaf(-li, xi, br));
      float ni = fmaf(lr, xi, fmaf(li, xr, bi));
      xr = nr; xi = ni;
      xre[base] = xr; xim[base] = xi;
      base -= 64;
    }
  }
}

// ---------------- C-projection + D*u + gelu + residual (in-place over fx) ----------------
__global__ __launch_bounds__(256) void k_proj(
    const float* __restrict__ xfre, const float* __restrict__ xfim,
    const float* __restrict__ xbre, const float* __restrict__ xbim,
    const float* __restrict__ Cre, const float* __restrict__ Cim,
    const float* __restrict__ Dv, float* __restrict__ fio) {
  __shared__ float tS[64][65];
  __shared__ float tF[64][65];
  const int tid = threadIdx.x, blk = blockIdx.x;
  const int bb = blk / (LSEQ / 64);
  const int l0 = (blk % (LSEQ / 64)) * 64;
  const size_t rowbase = ((size_t)bb * LSEQ + l0) * 64;
#pragma unroll
  for (int k = 0; k < 16; ++k) { int idx = tid + k * 256; tF[idx >> 6][idx & 63] = fio[rowbase + idx]; }
  const int pos = tid & 63, q = tid >> 6;
  float acc[16];
#pragma unroll
  for (int j = 0; j < 16; ++j) acc[j] = 0.f;
#pragma unroll 1
  for (int seg = 0; seg < 4; ++seg) {
    __syncthreads();   // prior-iteration tS reads done (also covers tF staging on seg 0)
    const float* sp = (seg == 0) ? xfre : (seg == 1) ? xfim : (seg == 2) ? xbre : xbim;
#pragma unroll
    for (int k = 0; k < 16; ++k) { int idx = tid + k * 256; tS[idx >> 6][idx & 63] = sp[rowbase + idx]; }
    __syncthreads();
    const float* Wb = (seg & 1) ? Cim : Cre;
    const int coff = (seg & 2) ? 64 : 0;
    const float sgn = (seg & 1) ? -2.f : 2.f;
    for (int c0 = 0; c0 < 64; c0 += 8) {
      float vv[8];
#pragma unroll
      for (int u = 0; u < 8; ++u) vv[u] = tS[pos][c0 + u];
#pragma unroll
      for (int j = 0; j < 16; ++j) {
        const float* wr = Wb + (q * 16 + j) * 128 + coff + c0;
        float d = 0.f;
#pragma unroll
        for (int u = 0; u < 8; ++u) d += wr[u] * vv[u];
        acc[j] += sgn * d;
      }
    }
  }
  __syncthreads();
  float outv[16];
#pragma unroll
  for (int j = 0; j < 16; ++j) {
    int hh = q * 16 + j;
    float u = tF[pos][hh];
    float hv = acc[j] + Dv[hh] * u;
    outv[j] = gelu_f(hv) + u;
  }
#pragma unroll
  for (int j = 0; j < 16; ++j) tS[pos][q * 16 + j] = outv[j];
  __syncthreads();
#pragma unroll
  for (int k = 0; k < 16; ++k) { int idx = tid + k * 256; fio[rowbase + idx] = tS[idx >> 6][idx & 63]; }
}

// ---------------- LN2 + FF(enc,dec) + residual ----------------
__global__ __launch_bounds__(256) void k_ff(
    const float* __restrict__ x2, const float* __restrict__ g, const float* __restrict__ be,
    const float* __restrict__ enc, const float* __restrict__ dec, float* __restrict__ yo) {
  __shared__ float tA[64][65];
  __shared__ float tB[64][65];
  const int tid = threadIdx.x, blk = blockIdx.x;
  const int bb = blk / (LSEQ / 64);
  const int l0 = (blk % (LSEQ / 64)) * 64;
  const size_t rowbase = ((size_t)bb * LSEQ + l0) * 64;
#pragma unroll
  for (int k = 0; k < 16; ++k) { int idx = tid + k * 256; tA[idx >> 6][idx & 63] = x2[rowbase + idx]; }
  __syncthreads();
  const int pos = tid & 63, q = tid >> 6;
  float s = 0.f, s2 = 0.f;
#pragma unroll
  for (int c = 0; c < 64; ++c) { float v = tA[pos][c]; s += v; s2 += v * v; }
  float mu = s * (1.f / 64.f);
  float rs = rsqrtf(fmaxf(s2 * (1.f / 64.f) - mu * mu, 0.f) + 1e-5f);
#pragma unroll
  for (int u = 0; u < 16; ++u) {
    int c = q * 16 + u;
    tB[pos][c] = (tA[pos][c] - mu) * rs * g[c] + be[c];
  }
  __syncthreads();
  // GEMM1: t = fx2 @ enc^T  -> tA[pos][o]
  float tacc[16];
#pragma unroll
  for (int j = 0; j < 16; ++j) tacc[j] = 0.f;
  for (int c0 = 0; c0 < 64; c0 += 8) {
    float vv[8];
#pragma unroll
    for (int u = 0; u < 8; ++u) vv[u] = tB[pos][c0 + u];
#pragma unroll
    for (int j = 0; j < 16; ++j) {
      const float* wr = enc + (q * 16 + j) * 64 + c0;
      float d = 0.f;
#pragma unroll
      for (int u = 0; u < 8; ++u) d += wr[u] * vv[u];
      tacc[j] += d;
    }
  }
#pragma unroll
  for (int j = 0; j < 16; ++j) tA[pos][q * 16 + j] = tacc[j];
  __syncthreads();
  // GEMM2: out = t @ dec^T + fx2
  float oacc[16];
#pragma unroll
  for (int j = 0; j < 16; ++j) oacc[j] = 0.f;
  for (int c0 = 0; c0 < 64; c0 += 8) {
    float vv[8];
#pragma unroll
    for (int u = 0; u < 8; ++u) vv[u] = tA[pos][c0 + u];
#pragma unroll
    for (int j = 0; j < 16; ++j) {
      const float* wr = dec + (q * 16 + j) * 64 + c0;
      float d = 0.f;
#pragma unroll
      for (int u = 0; u < 8; ++u) d += wr[u] * vv[u];
      oacc[j] += d;
    }
  }
#pragma unroll
  for (int j = 0; j < 16; ++j) oacc[j] += tB[pos][q * 16 + j];
  __syncthreads();
#pragma unroll
  for (int j = 0; j < 16; ++j) tA[pos][q * 16 + j] = oacc[j];
  __syncthreads();
#pragma unroll
  for (int k = 0; k < 16; ++k) { int idx = tid + k * 256; yo[rowbase + idx] = tA[idx >> 6][idx & 63]; }
}

// ---------------- 64x64 tiled transpose (b,C,H,W) -> (b,C,W,H) ----------------
__global__ __launch_bounds__(256) void k_transpose(const float* __restrict__ xin, float* __restrict__ xout) {
  __shared__ float t[64][65];
  const int tid = threadIdx.x, blk = blockIdx.x;
  const int bc = blk / 9, tt = blk % 9;
  const int h0 = (tt / 3) * 64, w0 = (tt % 3) * 64;
  const float* xp = xin + (size_t)bc * HH * WW;
  float* xq = xout + (size_t)bc * HH * WW;
#pragma unroll
  for (int k = 0; k < 16; ++k) {
    int idx = tid + k * 256; int r = idx >> 6, c = idx & 63;
    t[r][c] = xp[(size_t)(h0 + r) * WW + w0 + c];
  }
  __syncthreads();
#pragma unroll
  for (int k = 0; k < 16; ++k) {
    int idx = tid + k * 256; int r = idx >> 6, c = idx & 63;
    xq[(size_t)(w0 + r) * HH + h0 + c] = t[c][r];
  }
}

// ---------------- fusion: out[b,o,h,w] = W[o,:64].yh + W[o,64:].yv + bias ----------------
__global__ __launch_bounds__(256) void k_fusion(
    const float* __restrict__ yh, const float* __restrict__ yv,
    const float* __restrict__ Wf, const float* __restrict__ bf, float* __restrict__ out) {
  __shared__ float tA[64][65];
  __shared__ float tB[64][65];
  const int tid = threadIdx.x, blk = blockIdx.x;
  const int w0 = (blk % 3) * 64;
  const int hrow = (blk / 3) % HH;
  const int bb = blk / (3 * HH);
#pragma unroll
  for (int k = 0; k < 16; ++k) {
    int idx = tid + k * 256; int r = idx >> 6, c = idx & 63;
    tA[r][c] = yh[(((size_t)bb * LSEQ) + (size_t)hrow * WW + w0 + r) * 64 + c];
    tB[r][c] = yv[(((size_t)bb * LSEQ) + (size_t)(w0 + r) * HH + hrow) * 64 + c];
  }
  __syncthreads();
  const int pos = tid & 63, q = tid >> 6;
  float acc[16];
#pragma unroll
  for (int j = 0; j < 16; ++j) acc[j] = bf[q * 16 + j];
  for (int c0 = 0; c0 < 64; c0 += 8) {
    float va[8], vb[8];
#pragma unroll
    for (int u = 0; u < 8; ++u) { va[u] = tA[pos][c0 + u]; vb[u] = tB[pos][c0 + u]; }
#pragma unroll
    for (int j = 0; j < 16; ++j) {
      const float* wr = Wf + (q * 16 + j) * 128 + c0;
      float d = 0.f;
#pragma unroll
      for (int u = 0; u < 8; ++u) d += wr[u] * va[u];
#pragma unroll
      for (int u = 0; u < 8; ++u) d += wr[64 + u] * vb[u];
      acc[j] += d;
    }
  }
#pragma unroll
  for (int j = 0; j < 16; ++j) {
    int o = q * 16 + j;
    out[(((size_t)bb * 64 + o) * HH + hrow) * WW + w0 + pos] = acc[j];
  }
}

extern "C" void kernel_launch(void* const* d_in, const int* in_sizes, int n_in,
                              void* d_out, int out_size, void* d_ws, size_t ws_size,
                              hipStream_t stream) {
  (void)in_sizes; (void)n_in; (void)out_size; (void)ws_size;
  const float* x       = (const float*)d_in[0];
  const float* ln1_g   = (const float*)d_in[1];
  const float* ln1_b   = (const float*)d_in[2];
  const float* lam_re  = (const float*)d_in[3];
  const float* lam_im  = (const float*)d_in[4];
  const float* B_re    = (const float*)d_in[5];
  const float* B_im    = (const float*)d_in[6];
  const float* C_re    = (const float*)d_in[7];
  const float* C_im    = (const float*)d_in[8];
  const float* Dv      = (const float*)d_in[9];
  const float* log_st  = (const float*)d_in[10];
  const float* ln2_g   = (const float*)d_in[11];
  const float* ln2_b   = (const float*)d_in[12];
  const float* ff_enc  = (const float*)d_in[13];
  const float* ff_dec  = (const float*)d_in[14];
  const float* fus_w   = (const float*)d_in[15];
  const float* fus_b   = (const float*)d_in[16];

  float* ws   = (float*)d_ws;
  float* misc = ws;
  const size_t N1 = (size_t)4 * LSEQ * 64;     // 9,437,184 floats per region
  float* R0 = ws + MISC_N;                     // fx -> x2 (in place)
  float* R1 = R0 + N1;                         // Bu_re -> xb_re (in place)
  float* R2 = R1 + N1;                         // Bu_im -> xb_im (in place)
  float* R3 = R2 + N1;                         // xT (vert input) / xf_re
  float* R4 = R3 + N1;                         // xf_im
  float* R5 = R4 + N1;                         // y_h (b, l=h*W+w, c)
  float* R6 = R5 + N1;                         // y_v (b, l=w*H+h, c)
  float* carry = misc + CARRY_OFF;
  float* cin   = misc + CIN_OFF;

  k_setup<<<dim3(2), dim3(64), 0, stream>>>(lam_re, lam_im, B_re, B_im, log_st, misc);

  const int GB = 4 * (LSEQ / 64);  // 2304
  for (int i = 0; i < 2; ++i) {
    const float* xin = (i == 0) ? x : R3;
    float* yout = (i == 0) ? R5 : R6;
    const float* lre = misc + LAMRE_OFF + i * 64;
    const float* lim = misc + LAMIM_OFF + i * 64;

    k_ln_bu<<<dim3(GB), dim3(256), 0, stream>>>(
        xin, ln1_g + i * 64, ln1_b + i * 64, misc + BB_OFF + i * 8192, R0, R1, R2);
    k_scan1<<<dim3(512), dim3(256), 0, stream>>>(R1, R2, lre, lim, carry);
    k_scan2<<<dim3(1), dim3(512), 0, stream>>>(lre, lim, carry, cin);
    k_scan3<<<dim3(256), dim3(256), 0, stream>>>(R1, R2, lre, lim, cin, 0, R3, R4);
    k_scan3<<<dim3(256), dim3(256), 0, stream>>>(R1, R2, lre, lim, cin, 1, R1, R2);
    k_proj<<<dim3(GB), dim3(256), 0, stream>>>(
        R3, R4, R1, R2, C_re + i * 8192, C_im + i * 8192, Dv + i * 64, R0);
    k_ff<<<dim3(GB), dim3(256), 0, stream>>>(
        R0, ln2_g + i * 64, ln2_b + i * 64, ff_enc + i * 4096, ff_dec + i * 4096, yout);
    if (i == 0) {
      // prepare vertical-sequence input (b,C,W,H) into R3 (xf_re is dead now)
      k_transpose<<<dim3(4 * 64 * 9), dim3(256), 0, stream>>>(x, R3);
    }
  }
  k_fusion<<<dim3(4 * HH * 3), dim3(256), 0, stream>>>(R5, R6, fus_w, fus_b, (float*)d_out);
}

// Round 3
// 544.920 us; speedup vs baseline: 3.1561x; 3.1561x over previous
//
#include <hip/hip_runtime.h>
#include <math.h>

#define LSEQ 36864          // 192*192
#define NCH  512            // scan chunks
#define CLEN 72             // chunk length (512*72 = 36864)
#define HH   192
#define WW   192

typedef unsigned short u16;
typedef unsigned int   u32;
typedef __bf16 bf16x8 __attribute__((ext_vector_type(8)));
typedef float  f32x4  __attribute__((ext_vector_type(4)));

// ---- workspace layout (float-unit offsets from ws base), total <= 64M floats (256MiB) ----
#define LAMRE_OFF 0
#define LAMIM_OFF 128
#define CARRY_OFF 1024           // 4*2*512*64*2 = 524288 floats
#define CIN_OFF   600064         // 524288 floats  (ends < 2<<20)
#define OFF_W    (2u<<20)        // u16 weight region (4MB)
#define OFF_BU   (3u<<20)        // float2 (b,L,64) -> 18M floats, ends 21M
#define OFF_S    (21u<<20)       // u16 (b,L,256) states -> 18M float-equiv, ends 39M
#define OFF_FIO  (39u<<20)       // f32 (b,L,64) fx -> x2 in place, ends 48M
#define OFF_XT   (48u<<20)       // f32 (b,C,W,H), ends 57M; yv aliases its head after xT is dead
#define OFF_YH   (57u<<20)       // u16 (b,L,64) -> 4.5M float-equiv, ends 61.5M

// weight region layout (u16 offsets)
#define WO_BBH  0                // 2 x 128 x 64
#define WO_BBL  16384            // 2 x 128 x 64
#define WO_CC   32768            // 2 x 64 x 256
#define WO_ENC  65536            // 2 x 64 x 64
#define WO_DEC  73728            // 2 x 64 x 64
#define WO_FW   81920            // 64 x 128

__device__ __forceinline__ u16 f2b(float f) {
  u32 u = __float_as_uint(f);
  return (u16)((u + 0x7fffu + ((u >> 16) & 1u)) >> 16);
}
__device__ __forceinline__ float b2f(u16 h) { return __uint_as_float(((u32)h) << 16); }
__device__ __forceinline__ float gelu_f(float x) {
  float t = 0.79788456080286535588f * x * (1.f + 0.044715f * x * x);
  float e = __expf(2.f * t);
  float th = 1.f - 2.f / (e + 1.f);   // = tanh(t), robust at +-inf
  return 0.5f * x * (1.f + th);
}

// ---------------- setup: lam_bar, B_bar(hi/lo bf16), CC/ENC/DEC/FW (bf16) ----------------
__global__ void k_setup(const float* __restrict__ lam_re, const float* __restrict__ lam_im,
                        const float* __restrict__ B_re, const float* __restrict__ B_im,
                        const float* __restrict__ log_step,
                        const float* __restrict__ C_re, const float* __restrict__ C_im,
                        const float* __restrict__ ff_enc, const float* __restrict__ ff_dec,
                        const float* __restrict__ fus_w,
                        float* __restrict__ misc, u16* __restrict__ wreg) {
  const int i = blockIdx.x, p = threadIdx.x;
  const float lr = lam_re[i * 64 + p], li = lam_im[i * 64 + p];
  const float dt = expf(log_step[i * 64 + p]);
  const float er = expf(lr * dt);
  const float lbr = er * cosf(li * dt), lbi = er * sinf(li * dt);
  misc[LAMRE_OFF + i * 64 + p] = lbr;
  misc[LAMIM_OFF + i * 64 + p] = lbi;
  const float nr = lbr - 1.f, ni = lbi;
  const float den = lr * lr + li * li;
  const float fr = (nr * lr + ni * li) / den, fi = (ni * lr - nr * li) / den;
  for (int c = 0; c < 64; ++c) {
    float br = B_re[i * 4096 + p * 64 + c], bi = B_im[i * 4096 + p * 64 + c];
    float wre = fr * br - fi * bi;
    float wim = fr * bi + fi * br;
    u16 hre = f2b(wre), him = f2b(wim);
    wreg[WO_BBH + i * 8192 + p * 64 + c]        = hre;
    wreg[WO_BBH + i * 8192 + (64 + p) * 64 + c] = him;
    wreg[WO_BBL + i * 8192 + p * 64 + c]        = f2b(wre - b2f(hre));
    wreg[WO_BBL + i * 8192 + (64 + p) * 64 + c] = f2b(wim - b2f(him));
  }
  // CC rows h: k-layout [0:64]=2*Cre(:,0:64) [64:128]=-2*Cim(:,0:64) [128:192]=2*Cre(:,64:) [192:256]=-2*Cim(:,64:)
  const int h = p;
  for (int pp = 0; pp < 64; ++pp) {
    float cr0 = C_re[i * 8192 + h * 128 + pp],      ci0 = C_im[i * 8192 + h * 128 + pp];
    float cr1 = C_re[i * 8192 + h * 128 + 64 + pp], ci1 = C_im[i * 8192 + h * 128 + 64 + pp];
    wreg[WO_CC + i * 16384 + h * 256 + pp]        = f2b(2.f * cr0);
    wreg[WO_CC + i * 16384 + h * 256 + 64 + pp]   = f2b(-2.f * ci0);
    wreg[WO_CC + i * 16384 + h * 256 + 128 + pp]  = f2b(2.f * cr1);
    wreg[WO_CC + i * 16384 + h * 256 + 192 + pp]  = f2b(-2.f * ci1);
  }
  for (int c = 0; c < 64; ++c) {
    wreg[WO_ENC + i * 4096 + p * 64 + c] = f2b(ff_enc[i * 4096 + p * 64 + c]);
    wreg[WO_DEC + i * 4096 + p * 64 + c] = f2b(ff_dec[i * 4096 + p * 64 + c]);
  }
  if (i == 0) {
    for (int k = 0; k < 128; ++k) wreg[WO_FW + p * 128 + k] = f2b(fus_w[p * 128 + k]);
  }
}

// ---------------- LN1 + Bu GEMM (hi/lo split bf16 MFMA) ----------------
// xin: (b,C,L) f32.  fio: (b,L,64) f32 (fx).  bu: (b,L,64) float2 (re,im)
__global__ __launch_bounds__(256) void k_ln_bu(
    const float* __restrict__ xin, const float* __restrict__ g, const float* __restrict__ be,
    const u16* __restrict__ BBH, const u16* __restrict__ BBL,
    float* __restrict__ fio, float2* __restrict__ bu) {
  __shared__ float tBig[64][65];
  __shared__ __align__(16) u16 fh[64][88];
  __shared__ __align__(16) u16 fl[64][88];
  const int tid = threadIdx.x, blk = blockIdx.x;
  const int bb = blk / 576;
  const int l0 = (blk % 576) * 64;
  const float* xp = xin + (size_t)bb * 64 * LSEQ + l0;
#pragma unroll
  for (int k = 0; k < 16; ++k) {
    int idx = tid + k * 256; int r = idx >> 6, c = idx & 63;
    tBig[r][c] = xp[(size_t)r * LSEQ + c];
  }
  __syncthreads();
  const int pos = tid & 63, q = tid >> 6;
  float s = 0.f, s2 = 0.f;
#pragma unroll
  for (int c = 0; c < 64; ++c) { float v = tBig[c][pos]; s += v; s2 += v * v; }
  float mu = s * (1.f / 64.f);
  float rs = rsqrtf(fmaxf(s2 * (1.f / 64.f) - mu * mu, 0.f) + 1e-5f);
  const size_t gb = ((size_t)bb * LSEQ + l0) * 64;
#pragma unroll
  for (int u = 0; u < 16; ++u) {
    int c = q * 16 + u;
    float v = (tBig[c][pos] - mu) * rs * g[c] + be[c];
    u16 h = f2b(v);
    fh[pos][c] = h;
    fl[pos][c] = f2b(v - b2f(h));
    fio[gb + pos * 64 + c] = v;
  }
  __syncthreads();
  // MFMA: M=64 (4 waves x 16), N=128 (8 tiles), K=64, hi/lo split (hh + lh + hl)
  const int lane = tid & 63;
  const int m0 = q * 16;
  const int ar = m0 + (lane & 15);
  const int kb = (lane >> 4) * 8;
  bf16x8 a0h = *(const bf16x8*)&fh[ar][kb];
  bf16x8 a1h = *(const bf16x8*)&fh[ar][32 + kb];
  bf16x8 a0l = *(const bf16x8*)&fl[ar][kb];
  bf16x8 a1l = *(const bf16x8*)&fl[ar][32 + kb];
  f32x4 accs[8];
#pragma unroll
  for (int t = 0; t < 8; ++t) {
    const int wrow = (t * 16 + (lane & 15)) * 64 + kb;
    bf16x8 b0h = *(const bf16x8*)(BBH + wrow);
    bf16x8 b1h = *(const bf16x8*)(BBH + wrow + 32);
    bf16x8 b0l = *(const bf16x8*)(BBL + wrow);
    bf16x8 b1l = *(const bf16x8*)(BBL + wrow + 32);
    f32x4 acc = {0.f, 0.f, 0.f, 0.f};
    acc = __builtin_amdgcn_mfma_f32_16x16x32_bf16(a0h, b0h, acc, 0, 0, 0);
    acc = __builtin_amdgcn_mfma_f32_16x16x32_bf16(a0l, b0h, acc, 0, 0, 0);
    acc = __builtin_amdgcn_mfma_f32_16x16x32_bf16(a0h, b0l, acc, 0, 0, 0);
    acc = __builtin_amdgcn_mfma_f32_16x16x32_bf16(a1h, b1h, acc, 0, 0, 0);
    acc = __builtin_amdgcn_mfma_f32_16x16x32_bf16(a1l, b1h, acc, 0, 0, 0);
    acc = __builtin_amdgcn_mfma_f32_16x16x32_bf16(a1h, b1l, acc, 0, 0, 0);
    accs[t] = acc;
  }
  float2* bup = bu + (size_t)gb;  // (b,L,64) float2 base for this tile row
#pragma unroll
  for (int t = 0; t < 4; ++t) {
#pragma unroll
    for (int i = 0; i < 4; ++i) {
      int row = m0 + (lane >> 4) * 4 + i;
      float2 v; v.x = accs[t][i]; v.y = accs[t + 4][i];
      bup[row * 64 + t * 16 + (lane & 15)] = v;
    }
  }
}

// ---------------- scan phase 1: per-chunk local carries ----------------
__global__ __launch_bounds__(256) void k_scan1(
    const float2* __restrict__ bu, const float* __restrict__ lre, const float* __restrict__ lim,
    float* __restrict__ carry) {
  const int wid = blockIdx.x * 4 + (threadIdx.x >> 6);
  const int p = threadIdx.x & 63;
  const int chunk = wid & (NCH - 1);
  const int dir = (wid >> 9) & 1;
  const int bb = wid >> 10;
  const float lr = lre[p], li = lim[p];
  float xr = 0.f, xi = 0.f;
  if (dir == 0) {
    size_t base = ((size_t)bb * LSEQ + (size_t)chunk * CLEN) * 64 + p;
#pragma unroll 4
    for (int k = 0; k < CLEN; ++k) {
      float2 v = bu[base];
      float nr = fmaf(lr, xr, fmaf(-li, xi, v.x));
      float ni = fmaf(lr, xi, fmaf(li, xr, v.y));
      xr = nr; xi = ni; base += 64;
    }
  } else {
    size_t base = ((size_t)bb * LSEQ + (size_t)(LSEQ - 1 - chunk * CLEN)) * 64 + p;
#pragma unroll 4
    for (int k = 0; k < CLEN; ++k) {
      float2 v = bu[base];
      float nr = fmaf(lr, xr, fmaf(-li, xi, v.x));
      float ni = fmaf(lr, xi, fmaf(li, xr, v.y));
      xr = nr; xi = ni; base -= 64;
    }
  }
  size_t co = (((size_t)(bb * 2 + dir) * NCH + chunk) * 64 + p) * 2;
  carry[co] = xr; carry[co + 1] = xi;
}

// ---------------- scan phase 2: carry prefix (one wave per (b,dir)) ----------------
__global__ __launch_bounds__(64) void k_scan2(
    const float* __restrict__ lre, const float* __restrict__ lim,
    const float* __restrict__ carry, float* __restrict__ cin) {
  const int wv = blockIdx.x, p = threadIdx.x;
  const int dir = wv & 1, bb = wv >> 1;
  const float lr = lre[p], li = lim[p];
  float dr = 1.f, di = 0.f, br = lr, bi = li;   // lam^CLEN by squaring
  int e = CLEN;
  while (e) {
    if (e & 1) { float t = dr * br - di * bi; di = dr * bi + di * br; dr = t; }
    float t2 = br * br - bi * bi; bi = 2.f * br * bi; br = t2;
    e >>= 1;
  }
  float xr = 0.f, xi = 0.f;
  size_t base0 = ((size_t)(bb * 2 + dir) * NCH) * 64 + p;
#pragma unroll 4
  for (int j = 0; j < NCH; ++j) {
    size_t o = (base0 + (size_t)j * 64) * 2;
    cin[o] = xr; cin[o + 1] = xi;
    float cr = carry[o], ci = carry[o + 1];
    float nr = fmaf(dr, xr, fmaf(-di, xi, cr));
    float ni = fmaf(dr, xi, fmaf(di, xr, ci));
    xr = nr; xi = ni;
  }
}

// ---------------- scan phase 3: recompute with init, write bf16 states ----------------
// S layout (b,L,256): [0:64]=xf_re [64:128]=xf_im [128:192]=xb_re [192:256]=xb_im
__global__ __launch_bounds__(256) void k_scan3(
    const float2* __restrict__ bu, const float* __restrict__ lre, const float* __restrict__ lim,
    const float* __restrict__ cin, const int dir, u16* __restrict__ S) {
  const int wid = blockIdx.x * 4 + (threadIdx.x >> 6);
  const int p = threadIdx.x & 63;
  const int chunk = wid & (NCH - 1);
  const int bb = wid >> 9;
  const float lr = lre[p], li = lim[p];
  size_t co = (((size_t)(bb * 2 + dir) * NCH + chunk) * 64 + p) * 2;
  float xr = cin[co], xi = cin[co + 1];
  if (dir == 0) {
    size_t l = (size_t)bb * LSEQ + (size_t)chunk * CLEN;
#pragma unroll 4
    for (int k = 0; k < CLEN; ++k) {
      float2 v = bu[l * 64 + p];
      float nr = fmaf(lr, xr, fmaf(-li, xi, v.x));
      float ni = fmaf(lr, xi, fmaf(li, xr, v.y));
      xr = nr; xi = ni;
      S[l * 256 + p] = f2b(xr);
      S[l * 256 + 64 + p] = f2b(xi);
      l += 1;
    }
  } else {
    size_t l = (size_t)bb * LSEQ + (size_t)(LSEQ - 1 - chunk * CLEN);
#pragma unroll 4
    for (int k = 0; k < CLEN; ++k) {
      float2 v = bu[l * 64 + p];
      float nr = fmaf(lr, xr, fmaf(-li, xi, v.x));
      float ni = fmaf(lr, xi, fmaf(li, xr, v.y));
      xr = nr; xi = ni;
      S[l * 256 + 128 + p] = f2b(xr);
      S[l * 256 + 192 + p] = f2b(xi);
      l -= 1;
    }
  }
}

// ---------------- C-projection (MFMA, K=256) + D*u + gelu + residual (in-place f32) ----------------
__global__ __launch_bounds__(256) void k_proj(
    const u16* __restrict__ S, const u16* __restrict__ CCw, const float* __restrict__ Dv,
    float* fio) {   // fio read (fx) then written (x2) at the same per-thread indices
  const int tid = threadIdx.x, blk = blockIdx.x;
  const int bb = blk / 576;
  const int l0 = (blk % 576) * 64;
  const int lane = tid & 63;
  const int m0 = (tid >> 6) * 16;
  const int kb = (lane >> 4) * 8;
  const u16* Sp = S + ((size_t)bb * LSEQ + l0 + m0 + (lane & 15)) * 256 + kb;
  bf16x8 a[8];
#pragma unroll
  for (int kk = 0; kk < 8; ++kk) a[kk] = *(const bf16x8*)(Sp + kk * 32);
  const size_t gb = ((size_t)bb * LSEQ + l0) * 64;
#pragma unroll
  for (int t = 0; t < 4; ++t) {
    const u16* wp = CCw + (t * 16 + (lane & 15)) * 256 + kb;
    f32x4 acc = {0.f, 0.f, 0.f, 0.f};
#pragma unroll
    for (int kk = 0; kk < 8; ++kk)
      acc = __builtin_amdgcn_mfma_f32_16x16x32_bf16(a[kk], *(const bf16x8*)(wp + kk * 32), acc, 0, 0, 0);
    const int col = t * 16 + (lane & 15);
    const float dv = Dv[col];
#pragma unroll
    for (int i = 0; i < 4; ++i) {
      int row = m0 + (lane >> 4) * 4 + i;
      float u = fio[gb + row * 64 + col];
      float h = acc[i] + dv * u;
      fio[gb + row * 64 + col] = gelu_f(h) + u;
    }
  }
}

// ---------------- LN2 + FF (2x MFMA K=64) + residual ----------------
__global__ __launch_bounds__(256) void k_ff(
    const float* __restrict__ x2g, const float* __restrict__ g, const float* __restrict__ be,
    const u16* __restrict__ ENC, const u16* __restrict__ DEC, u16* __restrict__ yo) {
  __shared__ float xs[64][65];
  __shared__ __align__(16) u16 t1[64][88];
  __shared__ __align__(16) u16 t2[64][88];
  const int tid = threadIdx.x, blk = blockIdx.x;
  const int bb = blk / 576;
  const int l0 = (blk % 576) * 64;
  const size_t gb = ((size_t)bb * LSEQ + l0) * 64;
#pragma unroll
  for (int k = 0; k < 16; ++k) {
    int idx = tid + k * 256;
    xs[idx >> 6][idx & 63] = x2g[gb + idx];
  }
  __syncthreads();
  const int pos = tid & 63, q = tid >> 6;
  float s = 0.f, s2 = 0.f;
#pragma unroll
  for (int c = 0; c < 64; ++c) { float v = xs[pos][c]; s += v; s2 += v * v; }
  float mu = s * (1.f / 64.f);
  float rs = rsqrtf(fmaxf(s2 * (1.f / 64.f) - mu * mu, 0.f) + 1e-5f);
#pragma unroll
  for (int u = 0; u < 16; ++u) {
    int c = q * 16 + u;
    t2[pos][c] = f2b((xs[pos][c] - mu) * rs * g[c] + be[c]);
  }
  __syncthreads();
  // GEMM1: t = fx2 @ enc^T   (A from t2, out -> t1 as bf16)
  const int lane = tid & 63;
  const int m0 = q * 16;
  const int ar = m0 + (lane & 15);
  const int kb = (lane >> 4) * 8;
  bf16x8 a0 = *(const bf16x8*)&t2[ar][kb];
  bf16x8 a1 = *(const bf16x8*)&t2[ar][32 + kb];
  f32x4 accs[4];
#pragma unroll
  for (int t = 0; t < 4; ++t) {
    const u16* wp = ENC + (t * 16 + (lane & 15)) * 64 + kb;
    f32x4 acc = {0.f, 0.f, 0.f, 0.f};
    acc = __builtin_amdgcn_mfma_f32_16x16x32_bf16(a0, *(const bf16x8*)wp, acc, 0, 0, 0);
    acc = __builtin_amdgcn_mfma_f32_16x16x32_bf16(a1, *(const bf16x8*)(wp + 32), acc, 0, 0, 0);
    accs[t] = acc;
  }
  __syncthreads();
#pragma unroll
  for (int t = 0; t < 4; ++t)
#pragma unroll
    for (int i = 0; i < 4; ++i)
      t1[m0 + (lane >> 4) * 4 + i][t * 16 + (lane & 15)] = f2b(accs[t][i]);
  __syncthreads();
  // GEMM2: out = t @ dec^T + fx2
  bf16x8 c0 = *(const bf16x8*)&t1[ar][kb];
  bf16x8 c1 = *(const bf16x8*)&t1[ar][32 + kb];
#pragma unroll
  for (int t = 0; t < 4; ++t) {
    const u16* wp = DEC + (t * 16 + (lane & 15)) * 64 + kb;
    f32x4 acc = {0.f, 0.f, 0.f, 0.f};
    acc = __builtin_amdgcn_mfma_f32_16x16x32_bf16(c0, *(const bf16x8*)wp, acc, 0, 0, 0);
    acc = __builtin_amdgcn_mfma_f32_16x16x32_bf16(c1, *(const bf16x8*)(wp + 32), acc, 0, 0, 0);
#pragma unroll
    for (int i = 0; i < 4; ++i) {
      int row = m0 + (lane >> 4) * 4 + i;
      int col = t * 16 + (lane & 15);
      yo[gb + row * 64 + col] = f2b(acc[i] + b2f(t2[row][col]));
    }
  }
}

// ---------------- 64x64 tiled transpose (b,C,H,W) -> (b,C,W,H), f32 ----------------
__global__ __launch_bounds__(256) void k_transpose(const float* __restrict__ xin, float* __restrict__ xout) {
  __shared__ float t[64][65];
  const int tid = threadIdx.x, blk = blockIdx.x;
  const int bc = blk / 9, tt = blk % 9;
  const int h0 = (tt / 3) * 64, w0 = (tt % 3) * 64;
  const float* xp = xin + (size_t)bc * HH * WW;
  float* xq = xout + (size_t)bc * HH * WW;
#pragma unroll
  for (int k = 0; k < 16; ++k) {
    int idx = tid + k * 256; int r = idx >> 6, c = idx & 63;
    t[r][c] = xp[(size_t)(h0 + r) * WW + w0 + c];
  }
  __syncthreads();
#pragma unroll
  for (int k = 0; k < 16; ++k) {
    int idx = tid + k * 256; int r = idx >> 6, c = idx & 63;
    xq[(size_t)(w0 + r) * HH + h0 + c] = t[c][r];
  }
}

// ---------------- fusion (MFMA K=128) ----------------
__global__ __launch_bounds__(256) void k_fusion(
    const u16* __restrict__ yh, const u16* __restrict__ yv,
    const u16* __restrict__ FWw, const float* __restrict__ bf_, float* __restrict__ out) {
  __shared__ float ot[64][65];
  const int tid = threadIdx.x, blk = blockIdx.x;
  const int bb = blk / 576;
  const int rem = blk % 576;
  const int hrow = rem / 3;
  const int w0 = (rem % 3) * 64;
  const int lane = tid & 63;
  const int m0 = (tid >> 6) * 16;
  const int wrow = w0 + m0 + (lane & 15);
  const int kb = (lane >> 4) * 8;
  const u16* ah = yh + ((size_t)bb * LSEQ + (size_t)hrow * WW + wrow) * 64 + kb;
  const u16* av = yv + ((size_t)bb * LSEQ + (size_t)wrow * HH + hrow) * 64 + kb;
  bf16x8 a[4];
  a[0] = *(const bf16x8*)ah;
  a[1] = *(const bf16x8*)(ah + 32);
  a[2] = *(const bf16x8*)av;
  a[3] = *(const bf16x8*)(av + 32);
#pragma unroll
  for (int t = 0; t < 4; ++t) {
    const u16* wp = FWw + (t * 16 + (lane & 15)) * 128 + kb;
    f32x4 acc = {0.f, 0.f, 0.f, 0.f};
#pragma unroll
    for (int kk = 0; kk < 4; ++kk)
      acc = __builtin_amdgcn_mfma_f32_16x16x32_bf16(a[kk], *(const bf16x8*)(wp + kk * 32), acc, 0, 0, 0);
    const int col = t * 16 + (lane & 15);
#pragma unroll
    for (int i = 0; i < 4; ++i) ot[col][m0 + (lane >> 4) * 4 + i] = acc[i];
  }
  __syncthreads();
#pragma unroll
  for (int k = 0; k < 16; ++k) {
    int idx = tid + k * 256; int o = idx >> 6, wi = idx & 63;
    out[(((size_t)bb * 64 + o) * HH + hrow) * WW + w0 + wi] = ot[o][wi] + bf_[o];
  }
}

extern "C" void kernel_launch(void* const* d_in, const int* in_sizes, int n_in,
                              void* d_out, int out_size, void* d_ws, size_t ws_size,
                              hipStream_t stream) {
  (void)in_sizes; (void)n_in; (void)out_size; (void)ws_size;
  const float* x       = (const float*)d_in[0];
  const float* ln1_g   = (const float*)d_in[1];
  const float* ln1_b   = (const float*)d_in[2];
  const float* lam_re  = (const float*)d_in[3];
  const float* lam_im  = (const float*)d_in[4];
  const float* B_re    = (const float*)d_in[5];
  const float* B_im    = (const float*)d_in[6];
  const float* C_re    = (const float*)d_in[7];
  const float* C_im    = (const float*)d_in[8];
  const float* Dv      = (const float*)d_in[9];
  const float* log_st  = (const float*)d_in[10];
  const float* ln2_g   = (const float*)d_in[11];
  const float* ln2_b   = (const float*)d_in[12];
  const float* ff_enc  = (const float*)d_in[13];
  const float* ff_dec  = (const float*)d_in[14];
  const float* fus_w   = (const float*)d_in[15];
  const float* fus_b   = (const float*)d_in[16];

  float*  ws    = (float*)d_ws;
  float*  misc  = ws;
  u16*    wreg  = (u16*)(ws + OFF_W);
  float2* bu    = (float2*)(ws + OFF_BU);
  u16*    S     = (u16*)(ws + OFF_S);
  float*  fio   = ws + OFF_FIO;
  float*  xT    = ws + OFF_XT;
  u16*    yv    = (u16*)xT;            // alias: yv written only after xT's last read
  u16*    yh    = (u16*)(ws + OFF_YH);
  float*  carry = misc + CARRY_OFF;
  float*  cin   = misc + CIN_OFF;

  k_setup<<<dim3(2), dim3(64), 0, stream>>>(lam_re, lam_im, B_re, B_im, log_st,
                                            C_re, C_im, ff_enc, ff_dec, fus_w, misc, wreg);
  k_transpose<<<dim3(4 * 64 * 9), dim3(256), 0, stream>>>(x, xT);

  const int GB = 4 * (LSEQ / 64);  // 2304
  for (int i = 0; i < 2; ++i) {
    const float* xin = (i == 0) ? x : xT;
    u16* yout = (i == 0) ? yh : yv;
    const float* lre = misc + LAMRE_OFF + i * 64;
    const float* lim = misc + LAMIM_OFF + i * 64;

    k_ln_bu<<<dim3(GB), dim3(256), 0, stream>>>(
        xin, ln1_g + i * 64, ln1_b + i * 64,
        wreg + WO_BBH + i * 8192, wreg + WO_BBL + i * 8192, fio, bu);
    k_scan1<<<dim3(1024), dim3(256), 0, stream>>>(bu, lre, lim, carry);
    k_scan2<<<dim3(8), dim3(64), 0, stream>>>(lre, lim, carry, cin);
    k_scan3<<<dim3(512), dim3(256), 0, stream>>>(bu, lre, lim, cin, 0, S);
    k_scan3<<<dim3(512), dim3(256), 0, stream>>>(bu, lre, lim, cin, 1, S);
    k_proj<<<dim3(GB), dim3(256), 0, stream>>>(
        S, wreg + WO_CC + i * 16384, Dv + i * 64, fio);
    k_ff<<<dim3(GB), dim3(256), 0, stream>>>(
        fio, ln2_g + i * 64, ln2_b + i * 64, wreg + WO_ENC + i * 4096, wreg + WO_DEC + i * 4096, yout);
  }
  k_fusion<<<dim3(GB), dim3(256), 0, stream>>>(yh, yv, wreg + WO_FW, fus_b, (float*)d_out);
}

// Round 4
// 473.238 us; speedup vs baseline: 3.6342x; 1.1515x over previous
//
#include <hip/hip_runtime.h>
#include <math.h>

#define LSEQ 36864          // 192*192
#define HH   192
#define WW   192
#define NCHK 2304           // 16-position chunks per (b) per direction-of-scan
#define SEGC 144            // chunks per kB segment (16 segments)

typedef unsigned short u16;
typedef unsigned int   u32;
typedef __bf16 bf16x8 __attribute__((ext_vector_type(8)));
typedef float  f32x4  __attribute__((ext_vector_type(4)));

// ---- workspace layout (float-unit offsets) ----
#define LAMRE_OFF 0
#define LAMIM_OFF 128
#define OFF_CARF  1024
#define CAR_SZ    (4*NCHK*64*2)          // 1,179,648 floats
#define OFF_CARB  (OFF_CARF + CAR_SZ)
#define OFF_CINF  (OFF_CARB + CAR_SZ)
#define OFF_CINB  (OFF_CINF + CAR_SZ)
#define OFF_W     (OFF_CINB + CAR_SZ)    // u16 weight region (90112 u16)
#define OFF_FX    (OFF_W + 49152)        // u16 (b,L,64)  = 4,718,592 floats
#define FX_SZ     (4*LSEQ*64/2)
#define OFF_XT    (OFF_FX + FX_SZ)       // f32 (b,C,W,H) = 9,437,184 floats
#define OFF_YH    (OFF_XT + 4*LSEQ*64)   // u16 (b,L,64)
#define OFF_YV    (OFF_YH + FX_SZ)       // u16 (b,L,64)   ends ~28.4M floats (114MB)

// weight region layout (u16 offsets)
#define WO_BBH  0                // 2 x 128 x 64
#define WO_BBL  16384            // 2 x 128 x 64
#define WO_CC   32768            // 2 x 64 x 256
#define WO_ENC  65536            // 2 x 64 x 64
#define WO_DEC  73728            // 2 x 64 x 64
#define WO_FW   81920            // 64 x 128

__device__ __forceinline__ u16 f2b(float f) {
  u32 u = __float_as_uint(f);
  return (u16)((u + 0x7fffu + ((u >> 16) & 1u)) >> 16);
}
__device__ __forceinline__ float b2f(u16 h) { return __uint_as_float(((u32)h) << 16); }
__device__ __forceinline__ float gelu_f(float x) {
  float t = 0.79788456080286535588f * x * (1.f + 0.044715f * x * x);
  float e = __expf(2.f * t);
  float th = 1.f - 2.f / (e + 1.f);   // tanh(t), robust at +-inf
  return 0.5f * x * (1.f + th);
}

// ---------------- setup: lam_bar, B_bar(hi/lo bf16), CC/ENC/DEC/FW (bf16) ----------------
__global__ void k_setup(const float* __restrict__ lam_re, const float* __restrict__ lam_im,
                        const float* __restrict__ B_re, const float* __restrict__ B_im,
                        const float* __restrict__ log_step,
                        const float* __restrict__ C_re, const float* __restrict__ C_im,
                        const float* __restrict__ ff_enc, const float* __restrict__ ff_dec,
                        const float* __restrict__ fus_w,
                        float* __restrict__ misc, u16* __restrict__ wreg) {
  const int i = blockIdx.x, p = threadIdx.x;
  const float lr = lam_re[i * 64 + p], li = lam_im[i * 64 + p];
  const float dt = expf(log_step[i * 64 + p]);
  const float er = expf(lr * dt);
  const float lbr = er * cosf(li * dt), lbi = er * sinf(li * dt);
  misc[LAMRE_OFF + i * 64 + p] = lbr;
  misc[LAMIM_OFF + i * 64 + p] = lbi;
  const float nr = lbr - 1.f, ni = lbi;
  const float den = lr * lr + li * li;
  const float fr = (nr * lr + ni * li) / den, fi = (ni * lr - nr * li) / den;
  for (int c = 0; c < 64; ++c) {
    float br = B_re[i * 4096 + p * 64 + c], bi = B_im[i * 4096 + p * 64 + c];
    float wre = fr * br - fi * bi;
    float wim = fr * bi + fi * br;
    u16 hre = f2b(wre), him = f2b(wim);
    wreg[WO_BBH + i * 8192 + p * 64 + c]        = hre;
    wreg[WO_BBH + i * 8192 + (64 + p) * 64 + c] = him;
    wreg[WO_BBL + i * 8192 + p * 64 + c]        = f2b(wre - b2f(hre));
    wreg[WO_BBL + i * 8192 + (64 + p) * 64 + c] = f2b(wim - b2f(him));
  }
  const int h = p;
  for (int pp = 0; pp < 64; ++pp) {
    float cr0 = C_re[i * 8192 + h * 128 + pp],      ci0 = C_im[i * 8192 + h * 128 + pp];
    float cr1 = C_re[i * 8192 + h * 128 + 64 + pp], ci1 = C_im[i * 8192 + h * 128 + 64 + pp];
    wreg[WO_CC + i * 16384 + h * 256 + pp]        = f2b(2.f * cr0);
    wreg[WO_CC + i * 16384 + h * 256 + 64 + pp]   = f2b(-2.f * ci0);
    wreg[WO_CC + i * 16384 + h * 256 + 128 + pp]  = f2b(2.f * cr1);
    wreg[WO_CC + i * 16384 + h * 256 + 192 + pp]  = f2b(-2.f * ci1);
  }
  for (int c = 0; c < 64; ++c) {
    wreg[WO_ENC + i * 4096 + p * 64 + c] = f2b(ff_enc[i * 4096 + p * 64 + c]);
    wreg[WO_DEC + i * 4096 + p * 64 + c] = f2b(ff_dec[i * 4096 + p * 64 + c]);
  }
  if (i == 0) {
    for (int k = 0; k < 128; ++k) wreg[WO_FW + p * 128 + k] = f2b(fus_w[p * 128 + k]);
  }
}

// ---------------- kA: LN1 + Bu(hi/lo MFMA) + local 16-pos carries ----------------
__global__ __launch_bounds__(256) void kA(
    const float* __restrict__ xin, const float* __restrict__ g, const float* __restrict__ be,
    const u16* __restrict__ BBH, const u16* __restrict__ BBL,
    const float* __restrict__ lre, const float* __restrict__ lim,
    u16* __restrict__ fxo, float* __restrict__ carF, float* __restrict__ carB) {
  __shared__ float tBig[64][65];
  __shared__ __align__(16) u16 fh[64][88];
  __shared__ __align__(16) u16 fl[64][88];
  __shared__ float buR[64][65];
  __shared__ float buI[64][65];
  const int tid = threadIdx.x, blk = blockIdx.x;
  const int bb = blk / 576, t64 = blk % 576;
  const int l0 = t64 * 64;
  const float* xp = xin + (size_t)bb * 64 * LSEQ + l0;
#pragma unroll
  for (int k = 0; k < 16; ++k) {
    int idx = tid + k * 256; int r = idx >> 6, c = idx & 63;
    tBig[r][c] = xp[(size_t)r * LSEQ + c];
  }
  __syncthreads();
  const int pos = tid & 63, q = tid >> 6;
  float s = 0.f, s2 = 0.f;
#pragma unroll
  for (int c = 0; c < 64; ++c) { float v = tBig[c][pos]; s += v; s2 += v * v; }
  float mu = s * (1.f / 64.f);
  float rs = rsqrtf(fmaxf(s2 * (1.f / 64.f) - mu * mu, 0.f) + 1e-5f);
#pragma unroll
  for (int u = 0; u < 16; ++u) {
    int c = q * 16 + u;
    float v = (tBig[c][pos] - mu) * rs * g[c] + be[c];
    u16 h = f2b(v);
    fh[pos][c] = h;
    fl[pos][c] = f2b(v - b2f(h));
  }
  __syncthreads();
  // fx global write (u32 pairs)
  u32* fx32 = (u32*)fxo + ((size_t)bb * LSEQ + l0) * 32;
#pragma unroll
  for (int k = 0; k < 8; ++k) {
    int idx = tid + k * 256; int r = idx >> 5, cp = idx & 31;
    fx32[r * 32 + cp] = *(const u32*)&fh[r][cp * 2];
  }
  // hi/lo MFMA: M=64 pos, N=128 (re|im), K=64
  const int lane = tid & 63;
  const int m0 = q * 16;
  const int ar = m0 + (lane & 15);
  const int kb = (lane >> 4) * 8;
  bf16x8 a0h = *(const bf16x8*)&fh[ar][kb];
  bf16x8 a1h = *(const bf16x8*)&fh[ar][32 + kb];
  bf16x8 a0l = *(const bf16x8*)&fl[ar][kb];
  bf16x8 a1l = *(const bf16x8*)&fl[ar][32 + kb];
  f32x4 accs[8];
#pragma unroll
  for (int t = 0; t < 8; ++t) {
    const int wrow = (t * 16 + (lane & 15)) * 64 + kb;
    bf16x8 b0h = *(const bf16x8*)(BBH + wrow);
    bf16x8 b1h = *(const bf16x8*)(BBH + wrow + 32);
    bf16x8 b0l = *(const bf16x8*)(BBL + wrow);
    bf16x8 b1l = *(const bf16x8*)(BBL + wrow + 32);
    f32x4 acc = {0.f, 0.f, 0.f, 0.f};
    acc = __builtin_amdgcn_mfma_f32_16x16x32_bf16(a0h, b0h, acc, 0, 0, 0);
    acc = __builtin_amdgcn_mfma_f32_16x16x32_bf16(a0l, b0h, acc, 0, 0, 0);
    acc = __builtin_amdgcn_mfma_f32_16x16x32_bf16(a0h, b0l, acc, 0, 0, 0);
    acc = __builtin_amdgcn_mfma_f32_16x16x32_bf16(a1h, b1h, acc, 0, 0, 0);
    acc = __builtin_amdgcn_mfma_f32_16x16x32_bf16(a1l, b1h, acc, 0, 0, 0);
    acc = __builtin_amdgcn_mfma_f32_16x16x32_bf16(a1h, b1l, acc, 0, 0, 0);
    accs[t] = acc;
  }
#pragma unroll
  for (int t = 0; t < 4; ++t) {
#pragma unroll
    for (int i = 0; i < 4; ++i) {
      int row = m0 + (lane >> 4) * 4 + i;
      int p = t * 16 + (lane & 15);
      buR[row][p] = accs[t][i];
      buI[row][p] = accs[t + 4][i];
    }
  }
  __syncthreads();
  // local carries: wave q handles positions [16q, 16q+16)
  const float Lr = lre[pos], Li = lim[pos];
  float xr = 0.f, xi = 0.f;
#pragma unroll
  for (int j = 0; j < 16; ++j) {
    float br = buR[q * 16 + j][pos], bi = buI[q * 16 + j][pos];
    float nr2 = fmaf(Lr, xr, fmaf(-Li, xi, br));
    float ni2 = fmaf(Lr, xi, fmaf(Li, xr, bi));
    xr = nr2; xi = ni2;
  }
  size_t cf = (((size_t)bb * NCHK + t64 * 4 + q) * 64 + pos) * 2;
  carF[cf] = xr; carF[cf + 1] = xi;
  xr = 0.f; xi = 0.f;
#pragma unroll
  for (int j = 0; j < 16; ++j) {
    int pp = q * 16 + 15 - j;
    float br = buR[pp][pos], bi = buI[pp][pos];
    float nr2 = fmaf(Lr, xr, fmaf(-Li, xi, br));
    float ni2 = fmaf(Lr, xi, fmaf(Li, xr, bi));
    xr = nr2; xi = ni2;
  }
  size_t cb = (((size_t)bb * NCHK + (NCHK - 1 - t64 * 4 - q)) * 64 + pos) * 2;
  carB[cb] = xr; carB[cb + 1] = xi;
}

// ---------------- kB: chunk-carry prefix, segmented parallel scan ----------------
__global__ __launch_bounds__(1024) void kB(
    const float* __restrict__ lre, const float* __restrict__ lim,
    const float* __restrict__ carF, const float* __restrict__ carB,
    float* __restrict__ cinF, float* __restrict__ cinB) {
  __shared__ float Lw[16][64][2];
  const int fb = blockIdx.x & 1, bb = blockIdx.x >> 1;
  const int s = threadIdx.x >> 6, p = threadIdx.x & 63;
  const float* car = fb ? carB : carF;
  float* cin = fb ? cinB : cinF;
  const float lr = lre[p], li = lim[p];
  float mr = lr, mi = li;                 // lam^16 via 4 squarings
#pragma unroll
  for (int t = 0; t < 4; ++t) { float t2 = mr * mr - mi * mi; mi = 2.f * mr * mi; mr = t2; }
  float sr = 1.f, si = 0.f, br = mr, bi = mi;  // (lam^16)^SEGC
  int e = SEGC;
  while (e) {
    if (e & 1) { float t = sr * br - si * bi; si = sr * bi + si * br; sr = t; }
    float t2 = br * br - bi * bi; bi = 2.f * br * bi; br = t2;
    e >>= 1;
  }
  const size_t base = ((size_t)bb * NCHK + s * SEGC) * 64 + p;
  float xr = 0.f, xi = 0.f;
#pragma unroll 4
  for (int j = 0; j < SEGC; ++j) {
    size_t o = (base + (size_t)j * 64) * 2;
    float cr = car[o], ci = car[o + 1];
    float nr = fmaf(mr, xr, fmaf(-mi, xi, cr));
    float ni = fmaf(mr, xi, fmaf(mi, xr, ci));
    xr = nr; xi = ni;
  }
  Lw[s][p][0] = xr; Lw[s][p][1] = xi;
  __syncthreads();
  float ox = 0.f, oy = 0.f;
  for (int t = 0; t < s; ++t) {
    float cr = Lw[t][p][0], ci = Lw[t][p][1];
    float nr = fmaf(sr, ox, fmaf(-si, oy, cr));
    float ni = fmaf(sr, oy, fmaf(si, ox, ci));
    ox = nr; oy = ni;
  }
  xr = ox; xi = oy;
#pragma unroll 4
  for (int j = 0; j < SEGC; ++j) {
    size_t o = (base + (size_t)j * 64) * 2;
    cin[o] = xr; cin[o + 1] = xi;
    float cr = car[o], ci = car[o + 1];
    float nr = fmaf(mr, xr, fmaf(-mi, xi, cr));
    float ni = fmaf(mr, xi, fmaf(mi, xr, ci));
    xr = nr; xi = ni;
  }
}

// ---------------- kC: fx -> Bu(recompute) -> scan -> proj -> LN2 -> FF -> y ----------------
__global__ __launch_bounds__(256) void kC(
    const u16* __restrict__ fxg,
    const u16* __restrict__ BBH, const u16* __restrict__ BBL,
    const u16* __restrict__ CCw, const u16* __restrict__ ENC, const u16* __restrict__ DEC,
    const float* __restrict__ Dv, const float* __restrict__ g2, const float* __restrict__ b2v,
    const float* __restrict__ lre, const float* __restrict__ lim,
    const float* __restrict__ cinF, const float* __restrict__ cinB,
    u16* __restrict__ yo) {
  __shared__ __align__(16) u16 fh[64][88];
  __shared__ float buR[64][65];    // later reused as x2 tile (f32 [64][65])
  __shared__ float buI[64][65];
  __shared__ __align__(16) u16 S[64][264];   // later carved into t2/t1 [64][88] each
  const int tid = threadIdx.x, blk = blockIdx.x;
  const int bb = blk / 576, t64 = blk % 576;
  const int l0 = t64 * 64;
  const size_t gb = ((size_t)bb * LSEQ + l0) * 64;
  const u32* fx32 = (const u32*)fxg + ((size_t)bb * LSEQ + l0) * 32;
#pragma unroll
  for (int k = 0; k < 8; ++k) {
    int idx = tid + k * 256; int r = idx >> 5, cp = idx & 31;
    *(u32*)&fh[r][cp * 2] = fx32[r * 32 + cp];
  }
  __syncthreads();
  // --- Bu recompute: A = bf16 fx (exact), B = Wh + Wl ---
  const int pos = tid & 63, q = tid >> 6;
  const int lane = tid & 63;
  const int m0 = q * 16;
  const int ar = m0 + (lane & 15);
  const int kb = (lane >> 4) * 8;
  {
    bf16x8 a0 = *(const bf16x8*)&fh[ar][kb];
    bf16x8 a1 = *(const bf16x8*)&fh[ar][32 + kb];
    f32x4 accs[8];
#pragma unroll
    for (int t = 0; t < 8; ++t) {
      const int wrow = (t * 16 + (lane & 15)) * 64 + kb;
      bf16x8 b0h = *(const bf16x8*)(BBH + wrow);
      bf16x8 b1h = *(const bf16x8*)(BBH + wrow + 32);
      bf16x8 b0l = *(const bf16x8*)(BBL + wrow);
      bf16x8 b1l = *(const bf16x8*)(BBL + wrow + 32);
      f32x4 acc = {0.f, 0.f, 0.f, 0.f};
      acc = __builtin_amdgcn_mfma_f32_16x16x32_bf16(a0, b0h, acc, 0, 0, 0);
      acc = __builtin_amdgcn_mfma_f32_16x16x32_bf16(a0, b0l, acc, 0, 0, 0);
      acc = __builtin_amdgcn_mfma_f32_16x16x32_bf16(a1, b1h, acc, 0, 0, 0);
      acc = __builtin_amdgcn_mfma_f32_16x16x32_bf16(a1, b1l, acc, 0, 0, 0);
      accs[t] = acc;
    }
#pragma unroll
    for (int t = 0; t < 4; ++t) {
#pragma unroll
      for (int i = 0; i < 4; ++i) {
        int row = m0 + (lane >> 4) * 4 + i;
        int p = t * 16 + (lane & 15);
        buR[row][p] = accs[t][i];
        buI[row][p] = accs[t + 4][i];
      }
    }
  }
  __syncthreads();
  // --- scans with cin init; write bf16 S-tile ---
  {
    const float Lr = lre[pos], Li = lim[pos];
    size_t cf = (((size_t)bb * NCHK + t64 * 4 + q) * 64 + pos) * 2;
    float xr = cinF[cf], xi = cinF[cf + 1];
#pragma unroll
    for (int j = 0; j < 16; ++j) {
      int pp = q * 16 + j;
      float br = buR[pp][pos], bi = buI[pp][pos];
      float nr2 = fmaf(Lr, xr, fmaf(-Li, xi, br));
      float ni2 = fmaf(Lr, xi, fmaf(Li, xr, bi));
      xr = nr2; xi = ni2;
      S[pp][pos] = f2b(xr);
      S[pp][64 + pos] = f2b(xi);
    }
    size_t cb = (((size_t)bb * NCHK + (NCHK - 1 - t64 * 4 - q)) * 64 + pos) * 2;
    xr = cinB[cb]; xi = cinB[cb + 1];
#pragma unroll
    for (int j = 0; j < 16; ++j) {
      int pp = q * 16 + 15 - j;
      float br = buR[pp][pos], bi = buI[pp][pos];
      float nr2 = fmaf(Lr, xr, fmaf(-Li, xi, br));
      float ni2 = fmaf(Lr, xi, fmaf(Li, xr, bi));
      xr = nr2; xi = ni2;
      S[pp][128 + pos] = f2b(xr);
      S[pp][192 + pos] = f2b(xi);
    }
  }
  __syncthreads();
  // --- proj MFMA (K=256) + D*u + gelu + residual -> x2 tile (reuse buR) ---
  {
    bf16x8 a[8];
#pragma unroll
    for (int kk = 0; kk < 8; ++kk) a[kk] = *(const bf16x8*)&S[ar][kk * 32 + kb];
#pragma unroll
    for (int t = 0; t < 4; ++t) {
      const u16* wp = CCw + (t * 16 + (lane & 15)) * 256 + kb;
      f32x4 acc = {0.f, 0.f, 0.f, 0.f};
#pragma unroll
      for (int kk = 0; kk < 8; ++kk)
        acc = __builtin_amdgcn_mfma_f32_16x16x32_bf16(a[kk], *(const bf16x8*)(wp + kk * 32), acc, 0, 0, 0);
      const int col = t * 16 + (lane & 15);
      const float dv = Dv[col];
#pragma unroll
      for (int i = 0; i < 4; ++i) {
        int row = m0 + (lane >> 4) * 4 + i;
        float u = b2f(fh[row][col]);
        float h = acc[i] + dv * u;
        buR[row][col] = gelu_f(h) + u;   // x2 tile
      }
    }
  }
  __syncthreads();
  // --- LN2 (from x2 tile in buR) -> t2 bf16 ---
  u16 (*t2)[88] = (u16 (*)[88])(&S[0][0]);
  u16 (*t1)[88] = ((u16 (*)[88])(&S[0][0])) + 64;
  {
    float s = 0.f, s2 = 0.f;
#pragma unroll
    for (int c = 0; c < 64; ++c) { float v = buR[pos][c]; s += v; s2 += v * v; }
    float mu = s * (1.f / 64.f);
    float rs = rsqrtf(fmaxf(s2 * (1.f / 64.f) - mu * mu, 0.f) + 1e-5f);
#pragma unroll
    for (int u = 0; u < 16; ++u) {
      int c = q * 16 + u;
      t2[pos][c] = f2b((buR[pos][c] - mu) * rs * g2[c] + b2v[c]);
    }
  }
  __syncthreads();
  // --- FF GEMM1 ---
  {
    bf16x8 a0 = *(const bf16x8*)&t2[ar][kb];
    bf16x8 a1 = *(const bf16x8*)&t2[ar][32 + kb];
    f32x4 accs[4];
#pragma unroll
    for (int t = 0; t < 4; ++t) {
      const u16* wp = ENC + (t * 16 + (lane & 15)) * 64 + kb;
      f32x4 acc = {0.f, 0.f, 0.f, 0.f};
      acc = __builtin_amdgcn_mfma_f32_16x16x32_bf16(a0, *(const bf16x8*)wp, acc, 0, 0, 0);
      acc = __builtin_amdgcn_mfma_f32_16x16x32_bf16(a1, *(const bf16x8*)(wp + 32), acc, 0, 0, 0);
      accs[t] = acc;
    }
    __syncthreads();
#pragma unroll
    for (int t = 0; t < 4; ++t)
#pragma unroll
      for (int i = 0; i < 4; ++i)
        t1[m0 + (lane >> 4) * 4 + i][t * 16 + (lane & 15)] = f2b(accs[t][i]);
  }
  __syncthreads();
  // --- FF GEMM2 + residual -> y ---
  {
    bf16x8 c0 = *(const bf16x8*)&t1[ar][kb];
    bf16x8 c1 = *(const bf16x8*)&t1[ar][32 + kb];
#pragma unroll
    for (int t = 0; t < 4; ++t) {
      const u16* wp = DEC + (t * 16 + (lane & 15)) * 64 + kb;
      f32x4 acc = {0.f, 0.f, 0.f, 0.f};
      acc = __builtin_amdgcn_mfma_f32_16x16x32_bf16(c0, *(const bf16x8*)wp, acc, 0, 0, 0);
      acc = __builtin_amdgcn_mfma_f32_16x16x32_bf16(c1, *(const bf16x8*)(wp + 32), acc, 0, 0, 0);
#pragma unroll
      for (int i = 0; i < 4; ++i) {
        int row = m0 + (lane >> 4) * 4 + i;
        int col = t * 16 + (lane & 15);
        yo[gb + row * 64 + col] = f2b(acc[i] + b2f(t2[row][col]));
      }
    }
  }
}

// ---------------- 64x64 tiled transpose (b,C,H,W) -> (b,C,W,H), f32 ----------------
__global__ __launch_bounds__(256) void k_transpose(const float* __restrict__ xin, float* __restrict__ xout) {
  __shared__ float t[64][65];
  const int tid = threadIdx.x, blk = blockIdx.x;
  const int bc = blk / 9, tt = blk % 9;
  const int h0 = (tt / 3) * 64, w0 = (tt % 3) * 64;
  const float* xp = xin + (size_t)bc * HH * WW;
  float* xq = xout + (size_t)bc * HH * WW;
#pragma unroll
  for (int k = 0; k < 16; ++k) {
    int idx = tid + k * 256; int r = idx >> 6, c = idx & 63;
    t[r][c] = xp[(size_t)(h0 + r) * WW + w0 + c];
  }
  __syncthreads();
#pragma unroll
  for (int k = 0; k < 16; ++k) {
    int idx = tid + k * 256; int r = idx >> 6, c = idx & 63;
    xq[(size_t)(w0 + r) * HH + h0 + c] = t[c][r];
  }
}

// ---------------- fusion (MFMA K=128) ----------------
__global__ __launch_bounds__(256) void k_fusion(
    const u16* __restrict__ yh, const u16* __restrict__ yv,
    const u16* __restrict__ FWw, const float* __restrict__ bf_, float* __restrict__ out) {
  __shared__ float ot[64][65];
  const int tid = threadIdx.x, blk = blockIdx.x;
  const int bb = blk / 576;
  const int rem = blk % 576;
  const int hrow = rem / 3;
  const int w0 = (rem % 3) * 64;
  const int lane = tid & 63;
  const int m0 = (tid >> 6) * 16;
  const int wrow = w0 + m0 + (lane & 15);
  const int kb = (lane >> 4) * 8;
  const u16* ah = yh + ((size_t)bb * LSEQ + (size_t)hrow * WW + wrow) * 64 + kb;
  const u16* av = yv + ((size_t)bb * LSEQ + (size_t)wrow * HH + hrow) * 64 + kb;
  bf16x8 a[4];
  a[0] = *(const bf16x8*)ah;
  a[1] = *(const bf16x8*)(ah + 32);
  a[2] = *(const bf16x8*)av;
  a[3] = *(const bf16x8*)(av + 32);
#pragma unroll
  for (int t = 0; t < 4; ++t) {
    const u16* wp = FWw + (t * 16 + (lane & 15)) * 128 + kb;
    f32x4 acc = {0.f, 0.f, 0.f, 0.f};
#pragma unroll
    for (int kk = 0; kk < 4; ++kk)
      acc = __builtin_amdgcn_mfma_f32_16x16x32_bf16(a[kk], *(const bf16x8*)(wp + kk * 32), acc, 0, 0, 0);
    const int col = t * 16 + (lane & 15);
#pragma unroll
    for (int i = 0; i < 4; ++i) ot[col][m0 + (lane >> 4) * 4 + i] = acc[i];
  }
  __syncthreads();
#pragma unroll
  for (int k = 0; k < 16; ++k) {
    int idx = tid + k * 256; int o = idx >> 6, wi = idx & 63;
    out[(((size_t)bb * 64 + o) * HH + hrow) * WW + w0 + wi] = ot[o][wi] + bf_[o];
  }
}

extern "C" void kernel_launch(void* const* d_in, const int* in_sizes, int n_in,
                              void* d_out, int out_size, void* d_ws, size_t ws_size,
                              hipStream_t stream) {
  (void)in_sizes; (void)n_in; (void)out_size; (void)ws_size;
  const float* x       = (const float*)d_in[0];
  const float* ln1_g   = (const float*)d_in[1];
  const float* ln1_b   = (const float*)d_in[2];
  const float* lam_re  = (const float*)d_in[3];
  const float* lam_im  = (const float*)d_in[4];
  const float* B_re    = (const float*)d_in[5];
  const float* B_im    = (const float*)d_in[6];
  const float* C_re    = (const float*)d_in[7];
  const float* C_im    = (const float*)d_in[8];
  const float* Dv      = (const float*)d_in[9];
  const float* log_st  = (const float*)d_in[10];
  const float* ln2_g   = (const float*)d_in[11];
  const float* ln2_b   = (const float*)d_in[12];
  const float* ff_enc  = (const float*)d_in[13];
  const float* ff_dec  = (const float*)d_in[14];
  const float* fus_w   = (const float*)d_in[15];
  const float* fus_b   = (const float*)d_in[16];

  float* ws    = (float*)d_ws;
  float* misc  = ws;
  float* carF  = ws + OFF_CARF;
  float* carB  = ws + OFF_CARB;
  float* cinF  = ws + OFF_CINF;
  float* cinB  = ws + OFF_CINB;
  u16*   wreg  = (u16*)(ws + OFF_W);
  u16*   fxg   = (u16*)(ws + OFF_FX);
  float* xT    = ws + OFF_XT;
  u16*   yh    = (u16*)(ws + OFF_YH);
  u16*   yv    = (u16*)(ws + OFF_YV);

  k_setup<<<dim3(2), dim3(64), 0, stream>>>(lam_re, lam_im, B_re, B_im, log_st,
                                            C_re, C_im, ff_enc, ff_dec, fus_w, misc, wreg);
  k_transpose<<<dim3(4 * 64 * 9), dim3(256), 0, stream>>>(x, xT);

  const int GB = 4 * (LSEQ / 64);  // 2304
  for (int i = 0; i < 2; ++i) {
    const float* xin = (i == 0) ? x : xT;
    u16* yout = (i == 0) ? yh : yv;
    const float* lre = misc + LAMRE_OFF + i * 64;
    const float* lim = misc + LAMIM_OFF + i * 64;

    kA<<<dim3(GB), dim3(256), 0, stream>>>(
        xin, ln1_g + i * 64, ln1_b + i * 64,
        wreg + WO_BBH + i * 8192, wreg + WO_BBL + i * 8192,
        lre, lim, fxg, carF, carB);
    kB<<<dim3(8), dim3(1024), 0, stream>>>(lre, lim, carF, carB, cinF, cinB);
    kC<<<dim3(GB), dim3(256), 0, stream>>>(
        fxg, wreg + WO_BBH + i * 8192, wreg + WO_BBL + i * 8192,
        wreg + WO_CC + i * 16384, wreg + WO_ENC + i * 4096, wreg + WO_DEC + i * 4096,
        Dv + i * 64, ln2_g + i * 64, ln2_b + i * 64,
        lre, lim, cinF, cinB, yout);
  }
  k_fusion<<<dim3(GB), dim3(256), 0, stream>>>(yh, yv, wreg + WO_FW, fus_b, (float*)d_out);
}